// Round 1
// 343.377 us; speedup vs baseline: 1.0521x; 1.0521x over previous
//
#include <hip/hip_runtime.h>
#include <math.h>

#define BATCH 32768
#define DIM   256
#define NLAT  4096

typedef _Float16 f16x8 __attribute__((ext_vector_type(8)));
typedef float    f32x16 __attribute__((ext_vector_type(16)));

// ---------------------------------------------------------------------------
// ws byte offsets (total ~4.23 MB; proven budget from earlier rounds)
//   cbh   : fp16 normalized codebook [4096][256]            2 MB
//   cbinv : float [4096]
//   keys  : uint [32768][16]  packed (approx val | idx)     2 MB
//   hist  : int [4096]
//   sse   : double
// xh (fp16 x, 16 MB) lives in the FIRST HALF OF THE zq OUTPUT REGION as
// scratch: written by prep_kernel, read by vq_gemm_kernel, then fully
// overwritten by rescore_kernel's zq stores (stream-ordered, safe).
// ---------------------------------------------------------------------------
#define WS_CBH    0u
#define WS_CBINV  2097152u
#define WS_KEYS   2113536u
#define WS_HIST   4210688u
#define WS_SSE    4227072u

// Order-preserving float->uint, top 20 bits kept, low 12 bits = code idx.
__device__ inline uint kenc(float v, int idx) {
  uint b = __float_as_uint(v);
  uint o = (b & 0x80000000u) ? ~b : (b ^ 0x80000000u);
  return (o & 0xFFFFF000u) | (uint)idx;
}
__device__ inline float kdec(uint key) {
  uint u = key & 0xFFFFF000u;
  uint bits = (u & 0x80000000u) ? (u ^ 0x80000000u) : ~u;
  return __uint_as_float(bits);
}

// Fused prep: blocks [0,1024) normalize codebook -> fp16 cbh + cbinv;
// blocks [1024,5120) convert x -> fp16 xh (identical (_Float16) rounding
// to what vq_gemm previously did inline, so downstream bits are unchanged).
__global__ __launch_bounds__(256) void prep_kernel(
    const float* __restrict__ x, const float* __restrict__ cb,
    ushort* __restrict__ cbh, float* __restrict__ cbinv,
    ushort* __restrict__ xh) {
  int bid = blockIdx.x;
  if (bid < 1024) {
    int w = threadIdx.x >> 6, l = threadIdx.x & 63;
    int row = bid * 4 + w;
    const float4* cr = (const float4*)(cb + (size_t)row * DIM);
    float4 v = cr[l];
    float s = v.x * v.x + v.y * v.y + v.z * v.z + v.w * v.w;
    #pragma unroll
    for (int m = 32; m; m >>= 1) s += __shfl_xor(s, m, 64);
    float inv = 1.0f / fmaxf(sqrtf(s), 1e-12f);
    if (l == 0) cbinv[row] = inv;
    union { _Float16 h[4]; uint2 u; } pk;
    pk.h[0] = (_Float16)(v.x * inv);
    pk.h[1] = (_Float16)(v.y * inv);
    pk.h[2] = (_Float16)(v.z * inv);
    pk.h[3] = (_Float16)(v.w * inv);
    ((uint2*)cbh)[row * 64 + l] = pk.u;
  } else {
    int idx = (bid - 1024) * 256 + threadIdx.x;   // [0, 1048576)
    const float4* xs = (const float4*)x;
    float4 a = xs[idx * 2];
    float4 b = xs[idx * 2 + 1];
    union { _Float16 h[8]; uint4 u; } pk;
    pk.h[0] = (_Float16)a.x; pk.h[1] = (_Float16)a.y;
    pk.h[2] = (_Float16)a.z; pk.h[3] = (_Float16)a.w;
    pk.h[4] = (_Float16)b.x; pk.h[5] = (_Float16)b.y;
    pk.h[6] = (_Float16)b.z; pk.h[7] = (_Float16)b.w;
    ((uint4*)xh)[idx] = pk.u;
  }
}

// MFMA GEMM (codes x batch) + per-row top-4 candidate extraction.
// v2: NO LDS, NO BARRIERS. cbh (2 MB) is L2-resident; A-fragments are
// loaded straight from global into a 4-slot register ring, prefetch
// distance 2 (~512 cy of MFMA shadow vs ~200-400 cy L2 latency).
// grid 512: bb = bid>>2 (256 batch rows), q = bid&3 (1024-code quarter).
__global__ __launch_bounds__(256, 2) void vq_gemm_kernel(
    const ushort* __restrict__ xh, const uint4* __restrict__ cbh4,
    uint* __restrict__ keys) {
  const int tid = threadIdx.x;
  const int w = tid >> 6, l = tid & 63;
  const int l31 = l & 31, lh = l >> 5;
  const int bb = blockIdx.x >> 2, q = blockIdx.x & 3;
  const int wrow0 = bb * 256 + w * 64;
  const int cbase = q * 1024;

  // ---- x fragments (full K=256) into registers, direct fp16 loads ----
  f16x8 xf[16][2];
  #pragma unroll
  for (int fc = 0; fc < 2; ++fc) {
    const int row = wrow0 + fc * 32 + l31;
    const f16x8* xr = (const f16x8*)(xh + (size_t)row * DIM);
    #pragma unroll
    for (int s2 = 0; s2 < 16; ++s2) xf[s2][fc] = xr[s2 * 2 + lh];
  }

  // per-lane A base: element index (cbase+l31)*32 + lh (16B units)
  const f16x8* ab = (const f16x8*)cbh4 + ((size_t)(cbase + l31) * 32 + lh);

  // register ring, prefetch distance 2. step stp in [0,256):
  //   t = stp>>4, p = (stp>>3)&1, s = stp&7; fragment chunk = p*16+2s(+lh)
  f16x8 afb[4][2];
  auto LDA = [&](int slot, int stp) {
    int tt = stp >> 4, rem = stp & 15;
    int pp = rem >> 3, ss = rem & 7;
    const f16x8* a = ab + (tt * 2048 + pp * 16 + 2 * ss);
    afb[slot][0] = a[0];
    afb[slot][1] = a[1024];   // rf=1: +32 code rows * 32 chunks
  };

  LDA(0, 0);
  LDA(1, 1);

  // running top-3 per (lane, fc)
  float tv1[2] = { -3e38f, -3e38f }, tv2[2] = { -3e38f, -3e38f },
        tv3[2] = { -3e38f, -3e38f };
  int   ti1[2] = { 0, 0 }, ti2[2] = { 0, 0 }, ti3[2] = { 0, 0 };

  #pragma unroll 1
  for (int t = 0; t < 16; ++t) {
    f32x16 acc[2][2];
    #pragma unroll
    for (int rf = 0; rf < 2; ++rf)
      #pragma unroll
      for (int fc = 0; fc < 2; ++fc)
        #pragma unroll
        for (int r = 0; r < 16; ++r) acc[rf][fc][r] = 0.f;

    #pragma unroll
    for (int sl = 0; sl < 16; ++sl) {
      const int stp = t * 16 + sl;
      LDA((sl + 2) & 3, min(stp + 2, 255));
      #pragma unroll
      for (int rf = 0; rf < 2; ++rf)
        #pragma unroll
        for (int fc = 0; fc < 2; ++fc)
          acc[rf][fc] = __builtin_amdgcn_mfma_f32_32x32x16_f16(
              afb[sl & 3][rf], xf[sl][fc], acc[rf][fc], 0, 0, 0);
    }

    // top-3 update for this 64-code tile
    #pragma unroll
    for (int fc = 0; fc < 2; ++fc) {
      float m = acc[0][fc][0];
      #pragma unroll
      for (int rf = 0; rf < 2; ++rf)
        #pragma unroll
        for (int r = 0; r < 16; ++r) m = fmaxf(m, acc[rf][fc][r]);
      if (m > tv3[fc]) {   // rare after early tiles
        #pragma unroll
        for (int rf = 0; rf < 2; ++rf)
          #pragma unroll
          for (int r = 0; r < 16; ++r) {
            float v = acc[rf][fc][r];
            if (v > tv3[fc]) {
              int code = cbase + t * 64 + rf * 32 + (r & 3) + 8 * (r >> 2) + 4 * lh;
              if (v > tv1[fc]) {
                tv3[fc] = tv2[fc]; ti3[fc] = ti2[fc];
                tv2[fc] = tv1[fc]; ti2[fc] = ti1[fc];
                tv1[fc] = v;       ti1[fc] = code;
              } else if (v > tv2[fc]) {
                tv3[fc] = tv2[fc]; ti3[fc] = ti2[fc];
                tv2[fc] = v;       ti2[fc] = code;
              } else {
                tv3[fc] = v;       ti3[fc] = code;
              }
            }
          }
      }
    }
  }

  // ---- merge lane pair (l, l^32) -> per-(row,quarter) top-4 keys ----
  #pragma unroll
  for (int fc = 0; fc < 2; ++fc) {
    float pv[6]; int pi[6];
    pv[0] = tv1[fc]; pv[1] = tv2[fc]; pv[2] = tv3[fc];
    pi[0] = ti1[fc]; pi[1] = ti2[fc]; pi[2] = ti3[fc];
    #pragma unroll
    for (int k = 0; k < 3; ++k) {
      pv[3 + k] = __shfl_xor(pv[k], 32, 64);
      pi[3 + k] = __shfl_xor(pi[k], 32, 64);
    }
    if (lh == 0) {
      float bv[4] = { -3e38f, -3e38f, -3e38f, -3e38f };
      int   bi[4] = { 0x7fffffff, 0x7fffffff, 0x7fffffff, 0x7fffffff };
      #pragma unroll
      for (int e = 0; e < 6; ++e) {
        float v = pv[e]; int ci = pi[e];
        #pragma unroll
        for (int k = 0; k < 4; ++k) {
          bool better = (v > bv[k]) || (v == bv[k] && ci < bi[k]);
          if (better) {
            float tvv = bv[k]; int tci = bi[k];
            bv[k] = v; bi[k] = ci;
            v = tvv; ci = tci;
          }
        }
      }
      int row = wrow0 + fc * 32 + l31;
      #pragma unroll
      for (int k = 0; k < 4; ++k)
        keys[row * 16 + q * 4 + k] = kenc(bv[k], bi[k] & (NLAT - 1));
    }
  }
}

// Screened rescore: decode 16 candidate keys, exact-rescore only those
// within the rigorous fp16-error window (usually none beyond the max).
__global__ __launch_bounds__(256) void rescore_kernel(
    const float* __restrict__ x, const float* __restrict__ cb,
    const float* __restrict__ cbinv, const uint* __restrict__ keys,
    float* __restrict__ zq, float* __restrict__ out_idx,
    int* __restrict__ hist, double* __restrict__ sse) {
  __shared__ float part[4];
  int tid = threadIdx.x, w = tid >> 6, l = tid & 63;
  int row = blockIdx.x * 4 + w;
  const float4* xr = (const float4*)(x + (size_t)row * DIM);
  float4 xv = xr[l];
  float s0 = xv.x * xv.x + xv.y * xv.y + xv.z * xv.z + xv.w * xv.w;
  #pragma unroll
  for (int m = 32; m; m >>= 1) s0 += __shfl_xor(s0, m, 64);
  float xnorm = sqrtf(s0);
  float xinv = 1.0f / fmaxf(xnorm, 1e-12f);

  uint key = keys[row * 16 + (l & 15)];
  uint kmax = key;
  #pragma unroll
  for (int m = 1; m < 16; m <<= 1) {
    uint o = __shfl_xor(kmax, m, 64);
    kmax = (o > kmax) ? o : kmax;
  }
  float dmax = kdec(kmax);
  float thr = dmax - 2.0f * (3e-3f * xnorm);
  bool inwin = (kdec(key) >= thr) && (l < 16);
  unsigned long long mask = __ballot(inwin);
  int besti;
  if (__popcll(mask) == 1) {
    besti = (int)(kmax & 0xFFFu);       // provably the exact argmax
  } else {
    float bestv = -3e38f; besti = 0x7fffffff;
    unsigned long long mm = mask;
    while (mm) {
      int b = __ffsll(mm) - 1; mm &= mm - 1;
      int ci = (int)(__shfl(key, b, 64) & 0xFFFu);
      float cbi = cbinv[ci];
      const float4* cr = (const float4*)(cb + (size_t)ci * DIM);
      float4 cv = cr[l];
      float d = (xv.x * xinv) * (cv.x * cbi) + (xv.y * xinv) * (cv.y * cbi)
              + (xv.z * xinv) * (cv.z * cbi) + (xv.w * xinv) * (cv.w * cbi);
      #pragma unroll
      for (int m = 32; m; m >>= 1) d += __shfl_xor(d, m, 64);
      bool better = (d > bestv) || (d == bestv && ci < besti);
      bestv = better ? d : bestv;
      besti = better ? ci : besti;
    }
  }

  float4 zv = ((const float4*)(cb + (size_t)besti * DIM))[l];
  float4 o;
  o.x = xv.x + (zv.x - xv.x); o.y = xv.y + (zv.y - xv.y);
  o.z = xv.z + (zv.z - xv.z); o.w = xv.w + (zv.w - xv.w);
  ((float4*)(zq + (size_t)row * DIM))[l] = o;
  float dx = xv.x - zv.x, dy = xv.y - zv.y, dz = xv.z - zv.z, dw = xv.w - zv.w;
  float s = dx * dx + dy * dy + dz * dz + dw * dw;
  #pragma unroll
  for (int m = 32; m; m >>= 1) s += __shfl_xor(s, m, 64);
  if (l == 0) part[w] = s;
  __syncthreads();
  if (tid == 0)
    atomicAdd(sse, (double)((part[0] + part[1]) + (part[2] + part[3])));
  if (l == 0) {
    atomicAdd(&hist[besti], 1);
    out_idx[row] = (float)besti;
  }
}

// Entropy from histogram + final scalar losses.
__global__ __launch_bounds__(256) void finalize_kernel(
    const int* __restrict__ hist, const double* __restrict__ sse,
    float* __restrict__ outs) {
  int tid = threadIdx.x;
  double s = 0.0;
  for (int k = tid; k < NLAT; k += 256) {
    int c = hist[k];
    if (c > 0) {
      float p = (float)c * (1.0f / 32768.0f);
      s += (double)(p * logf(p));
    }
  }
  #pragma unroll
  for (int off = 32; off; off >>= 1) s += __shfl_xor(s, off, 64);
  __shared__ double part[4];
  int w = tid >> 6, l = tid & 63;
  if (l == 0) part[w] = s;
  __syncthreads();
  if (tid == 0) {
    double H = -((part[0] + part[1]) + (part[2] + part[3]));
    double qv = sse[0] * (1.0 / ((double)BATCH * (double)DIM));
    float qf = (float)qv;
    float Hf = (float)H;
    float ent_loss = -Hf;
    float vq = qf + 0.25f * qf + 0.1f * ent_loss;
    outs[0] = vq;
    outs[1] = qf;
    outs[2] = qf;
    outs[3] = ent_loss;
    outs[4] = Hf;
  }
}

extern "C" void kernel_launch(void* const* d_in, const int* in_sizes, int n_in,
                              void* d_out, int out_size, void* d_ws, size_t ws_size,
                              hipStream_t stream) {
  const float* x  = (const float*)d_in[0];
  const float* cb = (const float*)d_in[1];

  float* out     = (float*)d_out;
  float* zq      = out;
  float* scalars = out + (size_t)BATCH * DIM;
  float* oidx    = scalars + 5;

  char* wsb = (char*)d_ws;
  ushort* cbh   = (ushort*)(wsb + WS_CBH);
  float*  cbinv = (float*)(wsb + WS_CBINV);
  uint*   keys  = (uint*)(wsb + WS_KEYS);
  int*    hist  = (int*)(wsb + WS_HIST);
  double* sse   = (double*)(wsb + WS_SSE);

  // fp16 x scratch in the first 16 MB of the zq output region
  // (written by prep, read by vq_gemm, then overwritten by rescore's zq).
  ushort* xh = (ushort*)d_out;

  hipMemsetAsync(hist, 0, NLAT * sizeof(int) + sizeof(double), stream);

  prep_kernel<<<5120, 256, 0, stream>>>(x, cb, cbh, cbinv, xh);
  vq_gemm_kernel<<<512, 256, 0, stream>>>(xh, (const uint4*)cbh, keys);
  rescore_kernel<<<BATCH / 4, 256, 0, stream>>>(x, cb, cbinv, keys,
                                                zq, oidx, hist, sse);
  finalize_kernel<<<1, 256, 0, stream>>>(hist, sse, scalars);
}

// Round 2
// 262.078 us; speedup vs baseline: 1.3785x; 1.3102x over previous
//
#include <hip/hip_runtime.h>
#include <math.h>

#define BATCH 32768
#define DIM   256
#define NLAT  4096

typedef _Float16 f16x8 __attribute__((ext_vector_type(8)));
typedef float    f32x16 __attribute__((ext_vector_type(16)));

// ---------------------------------------------------------------------------
// ws byte offsets (total ~4.23 MB; proven budget from earlier rounds)
//   cbh   : fp16 normalized codebook [4096][256]            2 MB
//   cbinv : float [4096]
//   keys  : uint [32768][16]  packed (approx val | idx)     2 MB
//   hist  : int [4096]
//   sse   : double (legacy slot, unused now)
// xh (fp16 x, 16 MB) lives in the zq OUTPUT REGION as scratch (prep writes,
// vq_gemm reads, rescore overwrites with zq -- stream-ordered, safe).
// psse (8192 doubles, 64 KB) REUSES THE CBH REGION: vq_gemm is the last
// reader of cbh; rescore (writer) and finalize (reader) run after it.
// ---------------------------------------------------------------------------
#define WS_CBH    0u
#define WS_CBINV  2097152u
#define WS_KEYS   2113536u
#define WS_HIST   4210688u
#define WS_SSE    4227072u

// Order-preserving float->uint, top 20 bits kept, low 12 bits = code idx.
__device__ inline uint kenc(float v, int idx) {
  uint b = __float_as_uint(v);
  uint o = (b & 0x80000000u) ? ~b : (b ^ 0x80000000u);
  return (o & 0xFFFFF000u) | (uint)idx;
}
__device__ inline float kdec(uint key) {
  uint u = key & 0xFFFFF000u;
  uint bits = (u & 0x80000000u) ? (u ^ 0x80000000u) : ~u;
  return __uint_as_float(bits);
}

// Fused prep: blocks [0,1024) normalize codebook -> fp16 cbh + cbinv;
// blocks [1024,5120) convert x -> fp16 xh; block 5120 zeros hist
// (replaces the hipMemsetAsync dispatch).
__global__ __launch_bounds__(256) void prep_kernel(
    const float* __restrict__ x, const float* __restrict__ cb,
    ushort* __restrict__ cbh, float* __restrict__ cbinv,
    ushort* __restrict__ xh, int* __restrict__ hist) {
  int bid = blockIdx.x;
  if (bid < 1024) {
    int w = threadIdx.x >> 6, l = threadIdx.x & 63;
    int row = bid * 4 + w;
    const float4* cr = (const float4*)(cb + (size_t)row * DIM);
    float4 v = cr[l];
    float s = v.x * v.x + v.y * v.y + v.z * v.z + v.w * v.w;
    #pragma unroll
    for (int m = 32; m; m >>= 1) s += __shfl_xor(s, m, 64);
    float inv = 1.0f / fmaxf(sqrtf(s), 1e-12f);
    if (l == 0) cbinv[row] = inv;
    union { _Float16 h[4]; uint2 u; } pk;
    pk.h[0] = (_Float16)(v.x * inv);
    pk.h[1] = (_Float16)(v.y * inv);
    pk.h[2] = (_Float16)(v.z * inv);
    pk.h[3] = (_Float16)(v.w * inv);
    ((uint2*)cbh)[row * 64 + l] = pk.u;
  } else if (bid < 5120) {
    int idx = (bid - 1024) * 256 + threadIdx.x;   // [0, 1048576)
    const float4* xs = (const float4*)x;
    float4 a = xs[idx * 2];
    float4 b = xs[idx * 2 + 1];
    union { _Float16 h[8]; uint4 u; } pk;
    pk.h[0] = (_Float16)a.x; pk.h[1] = (_Float16)a.y;
    pk.h[2] = (_Float16)a.z; pk.h[3] = (_Float16)a.w;
    pk.h[4] = (_Float16)b.x; pk.h[5] = (_Float16)b.y;
    pk.h[6] = (_Float16)b.z; pk.h[7] = (_Float16)b.w;
    ((uint4*)xh)[idx] = pk.u;
  } else {
    for (int k = threadIdx.x; k < NLAT; k += 256) hist[k] = 0;
  }
}

// MFMA GEMM (codes x batch) + per-row top-4 candidate extraction.
// v3: no LDS/barriers; 4-slot register ring at PREFETCH DISTANCE 3;
// all in-loop A addresses are per-t base pointers + compile-time
// immediate offsets (no runtime address math on the load-issue path).
// grid 512: bb = bid>>2 (256 batch rows), q = bid&3 (1024-code quarter).
__global__ __launch_bounds__(256, 2) void vq_gemm_kernel(
    const ushort* __restrict__ xh, const uint4* __restrict__ cbh4,
    uint* __restrict__ keys) {
  const int tid = threadIdx.x;
  const int w = tid >> 6, l = tid & 63;
  const int l31 = l & 31, lh = l >> 5;
  const int bb = blockIdx.x >> 2, q = blockIdx.x & 3;
  const int wrow0 = bb * 256 + w * 64;
  const int cbase = q * 1024;

  // ---- x fragments (full K=256) into registers, direct fp16 loads ----
  f16x8 xf[16][2];
  #pragma unroll
  for (int fc = 0; fc < 2; ++fc) {
    const int row = wrow0 + fc * 32 + l31;
    const f16x8* xr = (const f16x8*)(xh + (size_t)row * DIM);
    #pragma unroll
    for (int s2 = 0; s2 < 16; ++s2) xf[s2][fc] = xr[s2 * 2 + lh];
  }

  // per-lane A bases (f16x8 units): code row cbase+l31 (+32 for rf=1),
  // chunk lh. Per t the base advances by 64 rows = 2048 chunks.
  const f16x8* a0 = (const f16x8*)cbh4 + ((size_t)(cbase + l31) * 32 + lh);
  const f16x8* a1 = a0 + 1024;

  // chunk offset within a t for k-step rem in [0,16): (rem>>3)*16+(rem&7)*2
  f16x8 afb[4][2];
  #pragma unroll
  for (int s = 0; s < 3; ++s) {          // prologue: stp 0,1,2
    afb[s][0] = a0[s * 2];
    afb[s][1] = a1[s * 2];
  }

  // running top-3 per (lane, fc)
  float tv1[2] = { -3e38f, -3e38f }, tv2[2] = { -3e38f, -3e38f },
        tv3[2] = { -3e38f, -3e38f };
  int   ti1[2] = { 0, 0 }, ti2[2] = { 0, 0 }, ti3[2] = { 0, 0 };

  #pragma unroll 1
  for (int t = 0; t < 16; ++t) {
    const f16x8* a0n = a0 + 2048;        // next-t bases (also used by the
    const f16x8* a1n = a1 + 2048;        // 3 crossover prefetches)
    f32x16 acc[2][2];
    #pragma unroll
    for (int rf = 0; rf < 2; ++rf)
      #pragma unroll
      for (int fc = 0; fc < 2; ++fc)
        #pragma unroll
        for (int r = 0; r < 16; ++r) acc[rf][fc][r] = 0.f;

    #pragma unroll
    for (int sl = 0; sl < 16; ++sl) {
      const int pf = sl + 3;             // compile-time
      const int slot = pf & 3;
      if (pf < 16) {
        const int off = ((pf >> 3) << 4) + ((pf & 7) << 1);
        afb[slot][0] = a0[off];
        afb[slot][1] = a1[off];
      } else {
        // crossover into next t (at t=15 these read past cbh into
        // cbinv/keys -- valid ws memory, values never consumed)
        const int off = (pf - 16) << 1;
        afb[slot][0] = a0n[off];
        afb[slot][1] = a1n[off];
      }
      #pragma unroll
      for (int rf = 0; rf < 2; ++rf)
        #pragma unroll
        for (int fc = 0; fc < 2; ++fc)
          acc[rf][fc] = __builtin_amdgcn_mfma_f32_32x32x16_f16(
              afb[sl & 3][rf], xf[sl][fc], acc[rf][fc], 0, 0, 0);
    }
    a0 = a0n; a1 = a1n;

    // top-3 update for this 64-code tile (shallow max tree first)
    #pragma unroll
    for (int fc = 0; fc < 2; ++fc) {
      float mm[8];
      #pragma unroll
      for (int j = 0; j < 8; ++j)
        mm[j] = fmaxf(fmaxf(acc[0][fc][j], acc[0][fc][j + 8]),
                      fmaxf(acc[1][fc][j], acc[1][fc][j + 8]));
      float m0 = fmaxf(fmaxf(mm[0], mm[1]), fmaxf(mm[2], mm[3]));
      float m1 = fmaxf(fmaxf(mm[4], mm[5]), fmaxf(mm[6], mm[7]));
      float m = fmaxf(m0, m1);
      if (m > tv3[fc]) {   // rare after early tiles
        #pragma unroll
        for (int rf = 0; rf < 2; ++rf)
          #pragma unroll
          for (int r = 0; r < 16; ++r) {
            float v = acc[rf][fc][r];
            if (v > tv3[fc]) {
              int code = cbase + t * 64 + rf * 32 + (r & 3) + 8 * (r >> 2) + 4 * lh;
              if (v > tv1[fc]) {
                tv3[fc] = tv2[fc]; ti3[fc] = ti2[fc];
                tv2[fc] = tv1[fc]; ti2[fc] = ti1[fc];
                tv1[fc] = v;       ti1[fc] = code;
              } else if (v > tv2[fc]) {
                tv3[fc] = tv2[fc]; ti3[fc] = ti2[fc];
                tv2[fc] = v;       ti2[fc] = code;
              } else {
                tv3[fc] = v;       ti3[fc] = code;
              }
            }
          }
      }
    }
  }

  // ---- merge lane pair (l, l^32) -> per-(row,quarter) top-4 keys ----
  #pragma unroll
  for (int fc = 0; fc < 2; ++fc) {
    float pv[6]; int pi[6];
    pv[0] = tv1[fc]; pv[1] = tv2[fc]; pv[2] = tv3[fc];
    pi[0] = ti1[fc]; pi[1] = ti2[fc]; pi[2] = ti3[fc];
    #pragma unroll
    for (int k = 0; k < 3; ++k) {
      pv[3 + k] = __shfl_xor(pv[k], 32, 64);
      pi[3 + k] = __shfl_xor(pi[k], 32, 64);
    }
    if (lh == 0) {
      float bv[4] = { -3e38f, -3e38f, -3e38f, -3e38f };
      int   bi[4] = { 0x7fffffff, 0x7fffffff, 0x7fffffff, 0x7fffffff };
      #pragma unroll
      for (int e = 0; e < 6; ++e) {
        float v = pv[e]; int ci = pi[e];
        #pragma unroll
        for (int k = 0; k < 4; ++k) {
          bool better = (v > bv[k]) || (v == bv[k] && ci < bi[k]);
          if (better) {
            float tvv = bv[k]; int tci = bi[k];
            bv[k] = v; bi[k] = ci;
            v = tvv; ci = tci;
          }
        }
      }
      int row = wrow0 + fc * 32 + l31;
      #pragma unroll
      for (int k = 0; k < 4; ++k)
        keys[row * 16 + q * 4 + k] = kenc(bv[k], bi[k] & (NLAT - 1));
    }
  }
}

// Screened rescore: decode 16 candidate keys, exact-rescore only those
// within the rigorous fp16-error window (usually none beyond the max).
// v3: NO single-address atomic -- per-block SSE partial into psse[].
__global__ __launch_bounds__(256) void rescore_kernel(
    const float* __restrict__ x, const float* __restrict__ cb,
    const float* __restrict__ cbinv, const uint* __restrict__ keys,
    float* __restrict__ zq, float* __restrict__ out_idx,
    int* __restrict__ hist, double* __restrict__ psse) {
  __shared__ float part[4];
  int tid = threadIdx.x, w = tid >> 6, l = tid & 63;
  int row = blockIdx.x * 4 + w;
  const float4* xr = (const float4*)(x + (size_t)row * DIM);
  float4 xv = xr[l];
  float s0 = xv.x * xv.x + xv.y * xv.y + xv.z * xv.z + xv.w * xv.w;
  #pragma unroll
  for (int m = 32; m; m >>= 1) s0 += __shfl_xor(s0, m, 64);
  float xnorm = sqrtf(s0);
  float xinv = 1.0f / fmaxf(xnorm, 1e-12f);

  uint key = keys[row * 16 + (l & 15)];
  uint kmax = key;
  #pragma unroll
  for (int m = 1; m < 16; m <<= 1) {
    uint o = __shfl_xor(kmax, m, 64);
    kmax = (o > kmax) ? o : kmax;
  }
  float dmax = kdec(kmax);
  float thr = dmax - 2.0f * (3e-3f * xnorm);
  bool inwin = (kdec(key) >= thr) && (l < 16);
  unsigned long long mask = __ballot(inwin);
  int besti;
  if (__popcll(mask) == 1) {
    besti = (int)(kmax & 0xFFFu);       // provably the exact argmax
  } else {
    float bestv = -3e38f; besti = 0x7fffffff;
    unsigned long long mm = mask;
    while (mm) {
      int b = __ffsll(mm) - 1; mm &= mm - 1;
      int ci = (int)(__shfl(key, b, 64) & 0xFFFu);
      float cbi = cbinv[ci];
      const float4* cr = (const float4*)(cb + (size_t)ci * DIM);
      float4 cv = cr[l];
      float d = (xv.x * xinv) * (cv.x * cbi) + (xv.y * xinv) * (cv.y * cbi)
              + (xv.z * xinv) * (cv.z * cbi) + (xv.w * xinv) * (cv.w * cbi);
      #pragma unroll
      for (int m = 32; m; m >>= 1) d += __shfl_xor(d, m, 64);
      bool better = (d > bestv) || (d == bestv && ci < besti);
      bestv = better ? d : bestv;
      besti = better ? ci : besti;
    }
  }

  float4 zv = ((const float4*)(cb + (size_t)besti * DIM))[l];
  float4 o;
  o.x = xv.x + (zv.x - xv.x); o.y = xv.y + (zv.y - xv.y);
  o.z = xv.z + (zv.z - xv.z); o.w = xv.w + (zv.w - xv.w);
  ((float4*)(zq + (size_t)row * DIM))[l] = o;
  float dx = xv.x - zv.x, dy = xv.y - zv.y, dz = xv.z - zv.z, dw = xv.w - zv.w;
  float s = dx * dx + dy * dy + dz * dz + dw * dw;
  #pragma unroll
  for (int m = 32; m; m >>= 1) s += __shfl_xor(s, m, 64);
  if (l == 0) part[w] = s;
  __syncthreads();
  if (tid == 0)
    psse[blockIdx.x] = (double)((part[0] + part[1]) + (part[2] + part[3]));
  if (l == 0) {
    atomicAdd(&hist[besti], 1);
    out_idx[row] = (float)besti;
  }
}

// Entropy from histogram + SSE partial reduction + final scalar losses.
__global__ __launch_bounds__(256) void finalize_kernel(
    const int* __restrict__ hist, const double* __restrict__ psse,
    float* __restrict__ outs) {
  int tid = threadIdx.x;
  double e = 0.0, s = 0.0;
  for (int k = tid; k < NLAT; k += 256) {
    int c = hist[k];
    if (c > 0) {
      float p = (float)c * (1.0f / 32768.0f);
      e += (double)(p * logf(p));
    }
  }
  for (int k = tid; k < BATCH / 4; k += 256) s += psse[k];
  #pragma unroll
  for (int off = 32; off; off >>= 1) {
    e += __shfl_xor(e, off, 64);
    s += __shfl_xor(s, off, 64);
  }
  __shared__ double pe[4], ps[4];
  int w = tid >> 6, l = tid & 63;
  if (l == 0) { pe[w] = e; ps[w] = s; }
  __syncthreads();
  if (tid == 0) {
    double H = -((pe[0] + pe[1]) + (pe[2] + pe[3]));
    double sse = (ps[0] + ps[1]) + (ps[2] + ps[3]);
    double qv = sse * (1.0 / ((double)BATCH * (double)DIM));
    float qf = (float)qv;
    float Hf = (float)H;
    float ent_loss = -Hf;
    float vq = qf + 0.25f * qf + 0.1f * ent_loss;
    outs[0] = vq;
    outs[1] = qf;
    outs[2] = qf;
    outs[3] = ent_loss;
    outs[4] = Hf;
  }
}

extern "C" void kernel_launch(void* const* d_in, const int* in_sizes, int n_in,
                              void* d_out, int out_size, void* d_ws, size_t ws_size,
                              hipStream_t stream) {
  const float* x  = (const float*)d_in[0];
  const float* cb = (const float*)d_in[1];

  float* out     = (float*)d_out;
  float* zq      = out;
  float* scalars = out + (size_t)BATCH * DIM;
  float* oidx    = scalars + 5;

  char* wsb = (char*)d_ws;
  ushort* cbh   = (ushort*)(wsb + WS_CBH);
  float*  cbinv = (float*)(wsb + WS_CBINV);
  uint*   keys  = (uint*)(wsb + WS_KEYS);
  int*    hist  = (int*)(wsb + WS_HIST);
  // per-block SSE partials reuse the cbh region (dead after vq_gemm)
  double* psse  = (double*)(wsb + WS_CBH);

  // fp16 x scratch in the first 16 MB of the zq output region
  ushort* xh = (ushort*)d_out;

  prep_kernel<<<5121, 256, 0, stream>>>(x, cb, cbh, cbinv, xh, hist);
  vq_gemm_kernel<<<512, 256, 0, stream>>>(xh, (const uint4*)cbh, keys);
  rescore_kernel<<<BATCH / 4, 256, 0, stream>>>(x, cb, cbinv, keys,
                                                zq, oidx, hist, psse);
  finalize_kernel<<<1, 256, 0, stream>>>(hist, psse, scalars);
}

// Round 4
// 244.431 us; speedup vs baseline: 1.4780x; 1.0722x over previous
//
#include <hip/hip_runtime.h>
#include <math.h>

#define BATCH 32768
#define DIM   256
#define NLAT  4096

typedef _Float16 f16x8 __attribute__((ext_vector_type(8)));
typedef float    f32x16 __attribute__((ext_vector_type(16)));

// ---------------------------------------------------------------------------
// ws byte offsets (total ~4.23 MB)
//   cbh   : fp16 normalized codebook [4096][256]            2 MB
//   cbinv : float [4096]
//   keys  : uint [32768][16]  packed (approx val | idx)     2 MB
//   hist  : int [4096]
// xh (fp16 x, 16 MB) lives in the zq OUTPUT REGION as scratch (prep writes,
// vq_gemm reads, rescore overwrites with zq -- stream-ordered, safe).
// psse (8192 doubles) reuses the cbh region (dead after vq_gemm).
// ---------------------------------------------------------------------------
#define WS_CBH    0u
#define WS_CBINV  2097152u
#define WS_KEYS   2113536u
#define WS_HIST   4210688u

// Order-preserving float->uint, top 20 bits kept, low 12 bits = code idx.
__device__ inline uint kenc(float v, int idx) {
  uint b = __float_as_uint(v);
  uint o = (b & 0x80000000u) ? ~b : (b ^ 0x80000000u);
  return (o & 0xFFFFF000u) | (uint)idx;
}
__device__ inline float kdec(uint key) {
  uint u = key & 0xFFFFF000u;
  uint bits = (u & 0x80000000u) ? (u ^ 0x80000000u) : ~u;
  return __uint_as_float(bits);
}

// global -> LDS direct DMA, 16 B per lane (dest = uniform base + lane*16)
__device__ inline void gload_lds16(const void* g, void* l) {
  __builtin_amdgcn_global_load_lds(
      (const __attribute__((address_space(1))) void*)g,
      (__attribute__((address_space(3))) void*)l, 16, 0, 0);
}

// Fused prep: blocks [0,1024) normalize codebook -> fp16 cbh + cbinv;
// blocks [1024,5120) convert x -> fp16 xh; block 5120 zeros hist.
__global__ __launch_bounds__(256) void prep_kernel(
    const float* __restrict__ x, const float* __restrict__ cb,
    ushort* __restrict__ cbh, float* __restrict__ cbinv,
    ushort* __restrict__ xh, int* __restrict__ hist) {
  int bid = blockIdx.x;
  if (bid < 1024) {
    int w = threadIdx.x >> 6, l = threadIdx.x & 63;
    int row = bid * 4 + w;
    const float4* cr = (const float4*)(cb + (size_t)row * DIM);
    float4 v = cr[l];
    float s = v.x * v.x + v.y * v.y + v.z * v.z + v.w * v.w;
    #pragma unroll
    for (int m = 32; m; m >>= 1) s += __shfl_xor(s, m, 64);
    float inv = 1.0f / fmaxf(sqrtf(s), 1e-12f);
    if (l == 0) cbinv[row] = inv;
    union { _Float16 h[4]; uint2 u; } pk;
    pk.h[0] = (_Float16)(v.x * inv);
    pk.h[1] = (_Float16)(v.y * inv);
    pk.h[2] = (_Float16)(v.z * inv);
    pk.h[3] = (_Float16)(v.w * inv);
    ((uint2*)cbh)[row * 64 + l] = pk.u;
  } else if (bid < 5120) {
    int idx = (bid - 1024) * 256 + threadIdx.x;   // [0, 1048576)
    const float4* xs = (const float4*)x;
    float4 a = xs[idx * 2];
    float4 b = xs[idx * 2 + 1];
    union { _Float16 h[8]; uint4 u; } pk;
    pk.h[0] = (_Float16)a.x; pk.h[1] = (_Float16)a.y;
    pk.h[2] = (_Float16)a.z; pk.h[3] = (_Float16)a.w;
    pk.h[4] = (_Float16)b.x; pk.h[5] = (_Float16)b.y;
    pk.h[6] = (_Float16)b.z; pk.h[7] = (_Float16)b.w;
    ((uint4*)xh)[idx] = pk.u;
  } else {
    for (int k = threadIdx.x; k < NLAT; k += 256) hist[k] = 0;
  }
}

// MFMA GEMM (codes x batch) + per-row top-4 candidate extraction.
// v4b: codebook tile staged in LDS via global_load_lds (coalesced 16B/lane),
// both-sides XOR swizzle (slot ^= row&7) for conflict-free ds_read_b128,
// double-buffered with ONE __syncthreads per tile. Buffer selection is a
// runtime BYTE OFFSET into smem (no LDS-pointer aggregate init -- the
// round-3 compile failure).
// grid 512: bb = bid>>2 (256 batch rows), q = bid&3 (1024-code quarter).
__global__ __launch_bounds__(256, 2) void vq_gemm_kernel(
    const ushort* __restrict__ xh, const uint4* __restrict__ cbh4,
    uint* __restrict__ keys) {
  __shared__ __align__(16) char smem[65536];

  const int tid = threadIdx.x;
  const int w = tid >> 6, l = tid & 63;
  const int l31 = l & 31, lh = l >> 5;
  const int bb = blockIdx.x >> 2, q = blockIdx.x & 3;
  const int wrow0 = bb * 256 + w * 64;
  const int cbase = q * 1024;

  // ---- x fragments (full K=256) into registers, one-time gathers ----
  f16x8 xf[16][2];
  #pragma unroll
  for (int fc = 0; fc < 2; ++fc) {
    const int row = wrow0 + fc * 32 + l31;
    const f16x8* xr = (const f16x8*)(xh + (size_t)row * DIM);
    #pragma unroll
    for (int s2 = 0; s2 < 16; ++s2) xf[s2][fc] = xr[s2 * 2 + lh];
  }

  // ---- staging: tile t = 64 codes x 512 B = 32 KB, 8 issues/thread ----
  // LDS layout: row r at [r*512, r*512+512); 16B slot p holds logical
  // chunk g = p ^ (r&7)  (read-side swizzle pre-applied to global source).
  auto STAGE = [&](int bufoff, int t) {
    const uint4* base = cbh4 + (size_t)(cbase + t * 64) * 32;
    #pragma unroll
    for (int s = 0; s < 8; ++s) {
      int i = s * 256 + tid;                 // linear 16B-slot index
      int r = i >> 5;
      int c = (i & 31) ^ (r & 7);            // inverse-swizzled source chunk
      gload_lds16(base + r * 32 + c, smem + bufoff + (s * 256 + w * 64) * 16);
    }
  };

  // per-lane read-address constants: chunk g = sl*2+lh of row m,
  // stored at slot g ^ (m&7); decompose: lhx = lh^(k7&1), kk = k7>>1,
  // byte col = ((sl^kk)<<5) | (lhx<<4).
  const int k7 = l31 & 7;
  const int colbase = l31 * 512 + ((lh ^ (k7 & 1)) << 4);
  const int kk = k7 >> 1;

  STAGE(0, 0);
  asm volatile("s_waitcnt vmcnt(0)" ::: "memory");
  __syncthreads();

  // running top-3 per (lane, fc)
  float tv1[2] = { -3e38f, -3e38f }, tv2[2] = { -3e38f, -3e38f },
        tv3[2] = { -3e38f, -3e38f };
  int   ti1[2] = { 0, 0 }, ti2[2] = { 0, 0 }, ti3[2] = { 0, 0 };

  int curoff = 0;
  #pragma unroll 1
  for (int t = 0; t < 16; ++t) {
    if (t < 15) STAGE(curoff ^ 32768, t + 1);   // prefetch next tile

    f32x16 acc[2][2];
    #pragma unroll
    for (int rf = 0; rf < 2; ++rf)
      #pragma unroll
      for (int fc = 0; fc < 2; ++fc)
        #pragma unroll
        for (int r = 0; r < 16; ++r) acc[rf][fc][r] = 0.f;

    const char* bp = smem + curoff;
    #pragma unroll
    for (int sl = 0; sl < 16; ++sl) {
      const char* ap = bp + colbase + (((sl ^ kk) & 15) << 5);
      f16x8 a0v = *(const f16x8*)(ap);
      f16x8 a1v = *(const f16x8*)(ap + 16384);   // rf=1: rows 32..63
      #pragma unroll
      for (int fc = 0; fc < 2; ++fc) {
        acc[0][fc] = __builtin_amdgcn_mfma_f32_32x32x16_f16(
            a0v, xf[sl][fc], acc[0][fc], 0, 0, 0);
        acc[1][fc] = __builtin_amdgcn_mfma_f32_32x32x16_f16(
            a1v, xf[sl][fc], acc[1][fc], 0, 0, 0);
      }
    }

    // top-3 update for this 64-code tile (shallow max tree first)
    #pragma unroll
    for (int fc = 0; fc < 2; ++fc) {
      float mm[8];
      #pragma unroll
      for (int j = 0; j < 8; ++j)
        mm[j] = fmaxf(fmaxf(acc[0][fc][j], acc[0][fc][j + 8]),
                      fmaxf(acc[1][fc][j], acc[1][fc][j + 8]));
      float m0 = fmaxf(fmaxf(mm[0], mm[1]), fmaxf(mm[2], mm[3]));
      float m1 = fmaxf(fmaxf(mm[4], mm[5]), fmaxf(mm[6], mm[7]));
      float m = fmaxf(m0, m1);
      if (m > tv3[fc]) {   // rare after early tiles
        #pragma unroll
        for (int rf = 0; rf < 2; ++rf)
          #pragma unroll
          for (int r = 0; r < 16; ++r) {
            float v = acc[rf][fc][r];
            if (v > tv3[fc]) {
              int code = cbase + t * 64 + rf * 32 + (r & 3) + 8 * (r >> 2) + 4 * lh;
              if (v > tv1[fc]) {
                tv3[fc] = tv2[fc]; ti3[fc] = ti2[fc];
                tv2[fc] = tv1[fc]; ti2[fc] = ti1[fc];
                tv1[fc] = v;       ti1[fc] = code;
              } else if (v > tv2[fc]) {
                tv3[fc] = tv2[fc]; ti3[fc] = ti2[fc];
                tv2[fc] = v;       ti2[fc] = code;
              } else {
                tv3[fc] = v;       ti3[fc] = code;
              }
            }
          }
      }
    }

    asm volatile("s_waitcnt vmcnt(0)" ::: "memory");  // t+1 loads landed
    __syncthreads();                                   // all waves done w/ bp
    curoff ^= 32768;
  }

  // ---- merge lane pair (l, l^32) -> per-(row,quarter) top-4 keys ----
  #pragma unroll
  for (int fc = 0; fc < 2; ++fc) {
    float pv[6]; int pi[6];
    pv[0] = tv1[fc]; pv[1] = tv2[fc]; pv[2] = tv3[fc];
    pi[0] = ti1[fc]; pi[1] = ti2[fc]; pi[2] = ti3[fc];
    #pragma unroll
    for (int k = 0; k < 3; ++k) {
      pv[3 + k] = __shfl_xor(pv[k], 32, 64);
      pi[3 + k] = __shfl_xor(pi[k], 32, 64);
    }
    if (lh == 0) {
      float bv[4] = { -3e38f, -3e38f, -3e38f, -3e38f };
      int   bi[4] = { 0x7fffffff, 0x7fffffff, 0x7fffffff, 0x7fffffff };
      #pragma unroll
      for (int e = 0; e < 6; ++e) {
        float v = pv[e]; int ci = pi[e];
        #pragma unroll
        for (int k = 0; k < 4; ++k) {
          bool better = (v > bv[k]) || (v == bv[k] && ci < bi[k]);
          if (better) {
            float tvv = bv[k]; int tci = bi[k];
            bv[k] = v; bi[k] = ci;
            v = tvv; ci = tci;
          }
        }
      }
      int row = wrow0 + fc * 32 + l31;
      #pragma unroll
      for (int k = 0; k < 4; ++k)
        keys[row * 16 + q * 4 + k] = kenc(bv[k], bi[k] & (NLAT - 1));
    }
  }
}

// Screened rescore: decode 16 candidate keys, exact-rescore only those
// within the rigorous fp16-error window; per-block SSE partial (no atomic).
__global__ __launch_bounds__(256) void rescore_kernel(
    const float* __restrict__ x, const float* __restrict__ cb,
    const float* __restrict__ cbinv, const uint* __restrict__ keys,
    float* __restrict__ zq, float* __restrict__ out_idx,
    int* __restrict__ hist, double* __restrict__ psse) {
  __shared__ float part[4];
  int tid = threadIdx.x, w = tid >> 6, l = tid & 63;
  int row = blockIdx.x * 4 + w;
  const float4* xr = (const float4*)(x + (size_t)row * DIM);
  float4 xv = xr[l];
  float s0 = xv.x * xv.x + xv.y * xv.y + xv.z * xv.z + xv.w * xv.w;
  #pragma unroll
  for (int m = 32; m; m >>= 1) s0 += __shfl_xor(s0, m, 64);
  float xnorm = sqrtf(s0);
  float xinv = 1.0f / fmaxf(xnorm, 1e-12f);

  uint key = keys[row * 16 + (l & 15)];
  uint kmax = key;
  #pragma unroll
  for (int m = 1; m < 16; m <<= 1) {
    uint o = __shfl_xor(kmax, m, 64);
    kmax = (o > kmax) ? o : kmax;
  }
  float dmax = kdec(kmax);
  float thr = dmax - 2.0f * (3e-3f * xnorm);
  bool inwin = (kdec(key) >= thr) && (l < 16);
  unsigned long long mask = __ballot(inwin);
  int besti;
  if (__popcll(mask) == 1) {
    besti = (int)(kmax & 0xFFFu);       // provably the exact argmax
  } else {
    float bestv = -3e38f; besti = 0x7fffffff;
    unsigned long long mm = mask;
    while (mm) {
      int b = __ffsll(mm) - 1; mm &= mm - 1;
      int ci = (int)(__shfl(key, b, 64) & 0xFFFu);
      float cbi = cbinv[ci];
      const float4* cr = (const float4*)(cb + (size_t)ci * DIM);
      float4 cv = cr[l];
      float d = (xv.x * xinv) * (cv.x * cbi) + (xv.y * xinv) * (cv.y * cbi)
              + (xv.z * xinv) * (cv.z * cbi) + (xv.w * xinv) * (cv.w * cbi);
      #pragma unroll
      for (int m = 32; m; m >>= 1) d += __shfl_xor(d, m, 64);
      bool better = (d > bestv) || (d == bestv && ci < besti);
      bestv = better ? d : bestv;
      besti = better ? ci : besti;
    }
  }

  float4 zv = ((const float4*)(cb + (size_t)besti * DIM))[l];
  float4 o;
  o.x = xv.x + (zv.x - xv.x); o.y = xv.y + (zv.y - xv.y);
  o.z = xv.z + (zv.z - xv.z); o.w = xv.w + (zv.w - xv.w);
  ((float4*)(zq + (size_t)row * DIM))[l] = o;
  float dx = xv.x - zv.x, dy = xv.y - zv.y, dz = xv.z - zv.z, dw = xv.w - zv.w;
  float s = dx * dx + dy * dy + dz * dz + dw * dw;
  #pragma unroll
  for (int m = 32; m; m >>= 1) s += __shfl_xor(s, m, 64);
  if (l == 0) part[w] = s;
  __syncthreads();
  if (tid == 0)
    psse[blockIdx.x] = (double)((part[0] + part[1]) + (part[2] + part[3]));
  if (l == 0) {
    atomicAdd(&hist[besti], 1);
    out_idx[row] = (float)besti;
  }
}

// Entropy from histogram + SSE partial reduction + final scalar losses.
__global__ __launch_bounds__(256) void finalize_kernel(
    const int* __restrict__ hist, const double* __restrict__ psse,
    float* __restrict__ outs) {
  int tid = threadIdx.x;
  double e = 0.0, s = 0.0;
  for (int k = tid; k < NLAT; k += 256) {
    int c = hist[k];
    if (c > 0) {
      float p = (float)c * (1.0f / 32768.0f);
      e += (double)(p * logf(p));
    }
  }
  for (int k = tid; k < BATCH / 4; k += 256) s += psse[k];
  #pragma unroll
  for (int off = 32; off; off >>= 1) {
    e += __shfl_xor(e, off, 64);
    s += __shfl_xor(s, off, 64);
  }
  __shared__ double pe[4], ps[4];
  int w = tid >> 6, l = tid & 63;
  if (l == 0) { pe[w] = e; ps[w] = s; }
  __syncthreads();
  if (tid == 0) {
    double H = -((pe[0] + pe[1]) + (pe[2] + pe[3]));
    double sse = (ps[0] + ps[1]) + (ps[2] + ps[3]);
    double qv = sse * (1.0 / ((double)BATCH * (double)DIM));
    float qf = (float)qv;
    float Hf = (float)H;
    float ent_loss = -Hf;
    float vq = qf + 0.25f * qf + 0.1f * ent_loss;
    outs[0] = vq;
    outs[1] = qf;
    outs[2] = qf;
    outs[3] = ent_loss;
    outs[4] = Hf;
  }
}

extern "C" void kernel_launch(void* const* d_in, const int* in_sizes, int n_in,
                              void* d_out, int out_size, void* d_ws, size_t ws_size,
                              hipStream_t stream) {
  const float* x  = (const float*)d_in[0];
  const float* cb = (const float*)d_in[1];

  float* out     = (float*)d_out;
  float* zq      = out;
  float* scalars = out + (size_t)BATCH * DIM;
  float* oidx    = scalars + 5;

  char* wsb = (char*)d_ws;
  ushort* cbh   = (ushort*)(wsb + WS_CBH);
  float*  cbinv = (float*)(wsb + WS_CBINV);
  uint*   keys  = (uint*)(wsb + WS_KEYS);
  int*    hist  = (int*)(wsb + WS_HIST);
  // per-block SSE partials reuse the cbh region (dead after vq_gemm)
  double* psse  = (double*)(wsb + WS_CBH);

  // fp16 x scratch in the first 16 MB of the zq output region
  ushort* xh = (ushort*)d_out;

  prep_kernel<<<5121, 256, 0, stream>>>(x, cb, cbh, cbinv, xh, hist);
  vq_gemm_kernel<<<512, 256, 0, stream>>>(xh, (const uint4*)cbh, keys);
  rescore_kernel<<<BATCH / 4, 256, 0, stream>>>(x, cb, cbinv, keys,
                                                zq, oidx, hist, psse);
  finalize_kernel<<<1, 256, 0, stream>>>(hist, psse, scalars);
}

// Round 5
// 230.948 us; speedup vs baseline: 1.5643x; 1.0584x over previous
//
#include <hip/hip_runtime.h>
#include <math.h>

#define BATCH 32768
#define DIM   256
#define NLAT  4096

typedef _Float16 f16x8 __attribute__((ext_vector_type(8)));
typedef float    f32x16 __attribute__((ext_vector_type(16)));

// ---------------------------------------------------------------------------
// ws byte offsets (total ~4.23 MB)
//   cbhf  : fp16 normalized codebook, FRAGMENT-MAJOR           2 MB
//           cbhf[t][sl][rf][lane] : t=code-tile(64), sl=K-slice(16B chunkpair),
//           rf=code half (32), lane=MFMA lane; byte off =
//           ((t*16+sl)*2+rf)*1024 + lane*16
//   cbinv : float [4096]
//   keys  : uint [32768][16]  packed (approx val | idx)        2 MB
//   hist  : int [4096]
// xh (fp16 x, 16 MB) lives in the zq OUTPUT REGION as scratch (prep writes,
// vq_gemm reads, rescore overwrites with zq -- stream-ordered, safe).
// psse (8192 doubles) reuses the cbhf region (dead after vq_gemm).
// ---------------------------------------------------------------------------
#define WS_CBH    0u
#define WS_CBINV  2097152u
#define WS_KEYS   2113536u
#define WS_HIST   4210688u

// Order-preserving float->uint, top 20 bits kept, low 12 bits = code idx.
__device__ inline uint kenc(float v, int idx) {
  uint b = __float_as_uint(v);
  uint o = (b & 0x80000000u) ? ~b : (b ^ 0x80000000u);
  return (o & 0xFFFFF000u) | (uint)idx;
}
__device__ inline float kdec(uint key) {
  uint u = key & 0xFFFFF000u;
  uint bits = (u & 0x80000000u) ? (u ^ 0x80000000u) : ~u;
  return __uint_as_float(bits);
}

// Fused prep: blocks [0,1024) normalize codebook -> fragment-major fp16
// cbhf + cbinv; blocks [1024,5120) convert x -> fp16 xh; block 5120 zeros
// hist. Rounding identical to prior rounds -> downstream bits unchanged.
__global__ __launch_bounds__(256) void prep_kernel(
    const float* __restrict__ x, const float* __restrict__ cb,
    ushort* __restrict__ cbhf, float* __restrict__ cbinv,
    ushort* __restrict__ xh, int* __restrict__ hist) {
  int bid = blockIdx.x;
  if (bid < 1024) {
    int w = threadIdx.x >> 6, l = threadIdx.x & 63;
    int row = bid * 4 + w;
    const float4* cr = (const float4*)(cb + (size_t)row * DIM);
    float4 v = cr[l];
    float s = v.x * v.x + v.y * v.y + v.z * v.z + v.w * v.w;
    #pragma unroll
    for (int m = 32; m; m >>= 1) s += __shfl_xor(s, m, 64);
    float inv = 1.0f / fmaxf(sqrtf(s), 1e-12f);
    if (l == 0) cbinv[row] = inv;
    union { _Float16 h[4]; uint2 u; } pk;
    pk.h[0] = (_Float16)(v.x * inv);
    pk.h[1] = (_Float16)(v.y * inv);
    pk.h[2] = (_Float16)(v.z * inv);
    pk.h[3] = (_Float16)(v.w * inv);
    // fragment-major scatter: lane l holds halves [4l,4l+4) of row `row`.
    // chunk g = l>>1 (8 halves), half-of-chunk = l&1.
    int t  = row >> 6, rf = (row >> 5) & 1, l31r = row & 31;
    int sl = l >> 2, lh2 = (l >> 1) & 1, half = l & 1;
    int lane = lh2 * 32 + l31r;
    ((uint2*)cbhf)[(((t * 16 + sl) * 2 + rf) << 7) + lane * 2 + half] = pk.u;
  } else if (bid < 5120) {
    int idx = (bid - 1024) * 256 + threadIdx.x;   // [0, 1048576)
    const float4* xs = (const float4*)x;
    float4 a = xs[idx * 2];
    float4 b = xs[idx * 2 + 1];
    union { _Float16 h[8]; uint4 u; } pk;
    pk.h[0] = (_Float16)a.x; pk.h[1] = (_Float16)a.y;
    pk.h[2] = (_Float16)a.z; pk.h[3] = (_Float16)a.w;
    pk.h[4] = (_Float16)b.x; pk.h[5] = (_Float16)b.y;
    pk.h[6] = (_Float16)b.z; pk.h[7] = (_Float16)b.w;
    ((uint4*)xh)[idx] = pk.u;
  } else {
    for (int k = threadIdx.x; k < NLAT; k += 256) hist[k] = 0;
  }
}

// MFMA GEMM (codes x batch) + per-row top-4 candidate extraction.
// v5: NO LDS, NO BARRIERS. Codebook is fragment-major, so each A-fragment
// is ONE coalesced 1024B global load (L1/L2-hit; 4 waves/block share the
// stream). 4-slot register ring, prefetch distance 3, single stream
// pointer bumped +2048/step with 0/+1024 immediates.
// grid 512: bb = bid>>2 (256 batch rows), q = bid&3 (1024-code quarter).
__global__ __launch_bounds__(256, 2) void vq_gemm_kernel(
    const ushort* __restrict__ xh, const char* __restrict__ cbhf,
    uint* __restrict__ keys) {
  const int tid = threadIdx.x;
  const int w = tid >> 6, l = tid & 63;
  const int l31 = l & 31, lh = l >> 5;
  const int bb = blockIdx.x >> 2, q = blockIdx.x & 3;
  const int wrow0 = bb * 256 + w * 64;
  const int cbase = q * 1024;

  // ---- x fragments (full K=256) into registers, one-time loads ----
  f16x8 xf[16][2];
  #pragma unroll
  for (int fc = 0; fc < 2; ++fc) {
    const int row = wrow0 + fc * 32 + l31;
    const f16x8* xr = (const f16x8*)(xh + (size_t)row * DIM);
    #pragma unroll
    for (int s2 = 0; s2 < 16; ++s2) xf[s2][fc] = xr[s2 * 2 + lh];
  }

  // ---- A-stream: linear walk of this quarter's fragment-major data ----
  // step stp = t*16+sl; fragment (stp, rf) at qbase + stp*2048 + rf*1024
  // + l*16.  pp = prefetch pointer (starts at stp=3 after prologue).
  const char* qbase = cbhf + (size_t)q * 524288 + (size_t)l * 16;
  f16x8 ring[4][2];
  #pragma unroll
  for (int s = 0; s < 3; ++s) {
    ring[s][0] = *(const f16x8*)(qbase + s * 2048);
    ring[s][1] = *(const f16x8*)(qbase + s * 2048 + 1024);
  }
  const char* pp = qbase + 6144;

  // running top-3 per (lane, fc)
  float tv1[2] = { -3e38f, -3e38f }, tv2[2] = { -3e38f, -3e38f },
        tv3[2] = { -3e38f, -3e38f };
  int   ti1[2] = { 0, 0 }, ti2[2] = { 0, 0 }, ti3[2] = { 0, 0 };

  #pragma unroll 1
  for (int t = 0; t < 16; ++t) {
    f32x16 acc[2][2];
    #pragma unroll
    for (int rf = 0; rf < 2; ++rf)
      #pragma unroll
      for (int fc = 0; fc < 2; ++fc)
        #pragma unroll
        for (int r = 0; r < 16; ++r) acc[rf][fc][r] = 0.f;

    #pragma unroll
    for (int sl = 0; sl < 16; ++sl) {
      // prefetch stp+3 (at t=15 tail this reads past the quarter into
      // cbinv/keys -- valid ws memory, values never consumed)
      ring[(sl + 3) & 3][0] = *(const f16x8*)(pp);
      ring[(sl + 3) & 3][1] = *(const f16x8*)(pp + 1024);
      pp += 2048;
      #pragma unroll
      for (int fc = 0; fc < 2; ++fc) {
        acc[0][fc] = __builtin_amdgcn_mfma_f32_32x32x16_f16(
            ring[sl & 3][0], xf[sl][fc], acc[0][fc], 0, 0, 0);
        acc[1][fc] = __builtin_amdgcn_mfma_f32_32x32x16_f16(
            ring[sl & 3][1], xf[sl][fc], acc[1][fc], 0, 0, 0);
      }
    }

    // top-3 update for this 64-code tile (shallow max tree first)
    #pragma unroll
    for (int fc = 0; fc < 2; ++fc) {
      float mm[8];
      #pragma unroll
      for (int j = 0; j < 8; ++j)
        mm[j] = fmaxf(fmaxf(acc[0][fc][j], acc[0][fc][j + 8]),
                      fmaxf(acc[1][fc][j], acc[1][fc][j + 8]));
      float m0 = fmaxf(fmaxf(mm[0], mm[1]), fmaxf(mm[2], mm[3]));
      float m1 = fmaxf(fmaxf(mm[4], mm[5]), fmaxf(mm[6], mm[7]));
      float m = fmaxf(m0, m1);
      if (m > tv3[fc]) {   // rare after early tiles
        #pragma unroll
        for (int rf = 0; rf < 2; ++rf)
          #pragma unroll
          for (int r = 0; r < 16; ++r) {
            float v = acc[rf][fc][r];
            if (v > tv3[fc]) {
              int code = cbase + t * 64 + rf * 32 + (r & 3) + 8 * (r >> 2) + 4 * lh;
              if (v > tv1[fc]) {
                tv3[fc] = tv2[fc]; ti3[fc] = ti2[fc];
                tv2[fc] = tv1[fc]; ti2[fc] = ti1[fc];
                tv1[fc] = v;       ti1[fc] = code;
              } else if (v > tv2[fc]) {
                tv3[fc] = tv2[fc]; ti3[fc] = ti2[fc];
                tv2[fc] = v;       ti2[fc] = code;
              } else {
                tv3[fc] = v;       ti3[fc] = code;
              }
            }
          }
      }
    }
  }

  // ---- merge lane pair (l, l^32) -> per-(row,quarter) top-4 keys ----
  #pragma unroll
  for (int fc = 0; fc < 2; ++fc) {
    float pv[6]; int pi[6];
    pv[0] = tv1[fc]; pv[1] = tv2[fc]; pv[2] = tv3[fc];
    pi[0] = ti1[fc]; pi[1] = ti2[fc]; pi[2] = ti3[fc];
    #pragma unroll
    for (int k = 0; k < 3; ++k) {
      pv[3 + k] = __shfl_xor(pv[k], 32, 64);
      pi[3 + k] = __shfl_xor(pi[k], 32, 64);
    }
    if (lh == 0) {
      float bv[4] = { -3e38f, -3e38f, -3e38f, -3e38f };
      int   bi[4] = { 0x7fffffff, 0x7fffffff, 0x7fffffff, 0x7fffffff };
      #pragma unroll
      for (int e = 0; e < 6; ++e) {
        float v = pv[e]; int ci = pi[e];
        #pragma unroll
        for (int k = 0; k < 4; ++k) {
          bool better = (v > bv[k]) || (v == bv[k] && ci < bi[k]);
          if (better) {
            float tvv = bv[k]; int tci = bi[k];
            bv[k] = v; bi[k] = ci;
            v = tvv; ci = tci;
          }
        }
      }
      int row = wrow0 + fc * 32 + l31;
      #pragma unroll
      for (int k = 0; k < 4; ++k)
        keys[row * 16 + q * 4 + k] = kenc(bv[k], bi[k] & (NLAT - 1));
    }
  }
}

// Screened rescore: decode 16 candidate keys, exact-rescore only those
// within the rigorous fp16-error window; per-block SSE partial (no atomic).
__global__ __launch_bounds__(256) void rescore_kernel(
    const float* __restrict__ x, const float* __restrict__ cb,
    const float* __restrict__ cbinv, const uint* __restrict__ keys,
    float* __restrict__ zq, float* __restrict__ out_idx,
    int* __restrict__ hist, double* __restrict__ psse) {
  __shared__ float part[4];
  int tid = threadIdx.x, w = tid >> 6, l = tid & 63;
  int row = blockIdx.x * 4 + w;
  const float4* xr = (const float4*)(x + (size_t)row * DIM);
  float4 xv = xr[l];
  float s0 = xv.x * xv.x + xv.y * xv.y + xv.z * xv.z + xv.w * xv.w;
  #pragma unroll
  for (int m = 32; m; m >>= 1) s0 += __shfl_xor(s0, m, 64);
  float xnorm = sqrtf(s0);
  float xinv = 1.0f / fmaxf(xnorm, 1e-12f);

  uint key = keys[row * 16 + (l & 15)];
  uint kmax = key;
  #pragma unroll
  for (int m = 1; m < 16; m <<= 1) {
    uint o = __shfl_xor(kmax, m, 64);
    kmax = (o > kmax) ? o : kmax;
  }
  float dmax = kdec(kmax);
  float thr = dmax - 2.0f * (3e-3f * xnorm);
  bool inwin = (kdec(key) >= thr) && (l < 16);
  unsigned long long mask = __ballot(inwin);
  int besti;
  if (__popcll(mask) == 1) {
    besti = (int)(kmax & 0xFFFu);       // provably the exact argmax
  } else {
    float bestv = -3e38f; besti = 0x7fffffff;
    unsigned long long mm = mask;
    while (mm) {
      int b = __ffsll(mm) - 1; mm &= mm - 1;
      int ci = (int)(__shfl(key, b, 64) & 0xFFFu);
      float cbi = cbinv[ci];
      const float4* cr = (const float4*)(cb + (size_t)ci * DIM);
      float4 cv = cr[l];
      float d = (xv.x * xinv) * (cv.x * cbi) + (xv.y * xinv) * (cv.y * cbi)
              + (xv.z * xinv) * (cv.z * cbi) + (xv.w * xinv) * (cv.w * cbi);
      #pragma unroll
      for (int m = 32; m; m >>= 1) d += __shfl_xor(d, m, 64);
      bool better = (d > bestv) || (d == bestv && ci < besti);
      bestv = better ? d : bestv;
      besti = better ? ci : besti;
    }
  }

  float4 zv = ((const float4*)(cb + (size_t)besti * DIM))[l];
  float4 o;
  o.x = xv.x + (zv.x - xv.x); o.y = xv.y + (zv.y - xv.y);
  o.z = xv.z + (zv.z - xv.z); o.w = xv.w + (zv.w - xv.w);
  ((float4*)(zq + (size_t)row * DIM))[l] = o;
  float dx = xv.x - zv.x, dy = xv.y - zv.y, dz = xv.z - zv.z, dw = xv.w - zv.w;
  float s = dx * dx + dy * dy + dz * dz + dw * dw;
  #pragma unroll
  for (int m = 32; m; m >>= 1) s += __shfl_xor(s, m, 64);
  if (l == 0) part[w] = s;
  __syncthreads();
  if (tid == 0)
    psse[blockIdx.x] = (double)((part[0] + part[1]) + (part[2] + part[3]));
  if (l == 0) {
    atomicAdd(&hist[besti], 1);
    out_idx[row] = (float)besti;
  }
}

// Entropy from histogram + SSE partial reduction + final scalar losses.
__global__ __launch_bounds__(256) void finalize_kernel(
    const int* __restrict__ hist, const double* __restrict__ psse,
    float* __restrict__ outs) {
  int tid = threadIdx.x;
  double e = 0.0, s = 0.0;
  for (int k = tid; k < NLAT; k += 256) {
    int c = hist[k];
    if (c > 0) {
      float p = (float)c * (1.0f / 32768.0f);
      e += (double)(p * logf(p));
    }
  }
  for (int k = tid; k < BATCH / 4; k += 256) s += psse[k];
  #pragma unroll
  for (int off = 32; off; off >>= 1) {
    e += __shfl_xor(e, off, 64);
    s += __shfl_xor(s, off, 64);
  }
  __shared__ double pe[4], ps[4];
  int w = tid >> 6, l = tid & 63;
  if (l == 0) { pe[w] = e; ps[w] = s; }
  __syncthreads();
  if (tid == 0) {
    double H = -((pe[0] + pe[1]) + (pe[2] + pe[3]));
    double sse = (ps[0] + ps[1]) + (ps[2] + ps[3]);
    double qv = sse * (1.0 / ((double)BATCH * (double)DIM));
    float qf = (float)qv;
    float Hf = (float)H;
    float ent_loss = -Hf;
    float vq = qf + 0.25f * qf + 0.1f * ent_loss;
    outs[0] = vq;
    outs[1] = qf;
    outs[2] = qf;
    outs[3] = ent_loss;
    outs[4] = Hf;
  }
}

extern "C" void kernel_launch(void* const* d_in, const int* in_sizes, int n_in,
                              void* d_out, int out_size, void* d_ws, size_t ws_size,
                              hipStream_t stream) {
  const float* x  = (const float*)d_in[0];
  const float* cb = (const float*)d_in[1];

  float* out     = (float*)d_out;
  float* zq      = out;
  float* scalars = out + (size_t)BATCH * DIM;
  float* oidx    = scalars + 5;

  char* wsb = (char*)d_ws;
  ushort* cbhf  = (ushort*)(wsb + WS_CBH);
  float*  cbinv = (float*)(wsb + WS_CBINV);
  uint*   keys  = (uint*)(wsb + WS_KEYS);
  int*    hist  = (int*)(wsb + WS_HIST);
  // per-block SSE partials reuse the cbhf region (dead after vq_gemm)
  double* psse  = (double*)(wsb + WS_CBH);

  // fp16 x scratch in the first 16 MB of the zq output region
  ushort* xh = (ushort*)d_out;

  prep_kernel<<<5121, 256, 0, stream>>>(x, cb, cbhf, cbinv, xh, hist);
  vq_gemm_kernel<<<512, 256, 0, stream>>>(xh, (const char*)cbhf, keys);
  rescore_kernel<<<BATCH / 4, 256, 0, stream>>>(x, cb, cbinv, keys,
                                                zq, oidx, hist, psse);
  finalize_kernel<<<1, 256, 0, stream>>>(hist, psse, scalars);
}

// Round 6
// 222.264 us; speedup vs baseline: 1.6254x; 1.0391x over previous
//
#include <hip/hip_runtime.h>
#include <math.h>

#define BATCH 32768
#define DIM   256
#define NLAT  4096

typedef _Float16 f16x8 __attribute__((ext_vector_type(8)));
typedef float    f32x16 __attribute__((ext_vector_type(16)));

// ---------------------------------------------------------------------------
// ws byte offsets (total ~4.23 MB)
//   cbhf  : fp16 normalized codebook, FRAGMENT-MAJOR           2 MB
//           byte off = ((t*16+sl)*2+rf)*1024 + lane*16
//   cbinv : float [4096]
//   keys  : uint [32768][16]  BIASED-FLOAT-PACKED (val|idx)    2 MB
//   hist  : int [4096]
// xhf (fp16 x, FRAGMENT-MAJOR, 16 MB) lives in the zq OUTPUT REGION as
// scratch (prep writes, vq_gemm reads, rescore overwrites with zq).
//   uint4 idx = (rowgrp*16 + sl)*64 + lh*32 + (row&31),  rowgrp = row>>5
// psse (8192 doubles) reuses the cbhf region (dead after vq_gemm).
//
// KEY FORMAT (round 6): acc is biased +32.0 -> all values positive floats
// in (12,52) -> raw float bits are u32-ordered. key = (bits & 0xFFFFF000)
// | code(12b). kdec(key) = asfloat(key & 0xFFFFF000) (biased; all rescore
// compares are relative so bias cancels). Truncation err <= 0.0156 abs
// = 1.2e-3*||x|| at ||x||min~13, within the 2*(3e-3*||x||) window budget.
// ---------------------------------------------------------------------------
#define WS_CBH    0u
#define WS_CBINV  2097152u
#define WS_KEYS   2113536u
#define WS_HIST   4210688u

__device__ inline float kdec(uint key) {
  return __uint_as_float(key & 0xFFFFF000u);
}

// Fused prep: blocks [0,1024) normalize codebook -> fragment-major fp16
// cbhf + cbinv; blocks [1024,5120) convert x -> FRAGMENT-MAJOR fp16 xhf;
// block 5120 zeros hist. (_Float16) rounding identical to prior rounds.
__global__ __launch_bounds__(256) void prep_kernel(
    const float* __restrict__ x, const float* __restrict__ cb,
    ushort* __restrict__ cbhf, float* __restrict__ cbinv,
    ushort* __restrict__ xhf, int* __restrict__ hist) {
  int bid = blockIdx.x;
  if (bid < 1024) {
    int w = threadIdx.x >> 6, l = threadIdx.x & 63;
    int row = bid * 4 + w;
    const float4* cr = (const float4*)(cb + (size_t)row * DIM);
    float4 v = cr[l];
    float s = v.x * v.x + v.y * v.y + v.z * v.z + v.w * v.w;
    #pragma unroll
    for (int m = 32; m; m >>= 1) s += __shfl_xor(s, m, 64);
    float inv = 1.0f / fmaxf(sqrtf(s), 1e-12f);
    if (l == 0) cbinv[row] = inv;
    union { _Float16 h[4]; uint2 u; } pk;
    pk.h[0] = (_Float16)(v.x * inv);
    pk.h[1] = (_Float16)(v.y * inv);
    pk.h[2] = (_Float16)(v.z * inv);
    pk.h[3] = (_Float16)(v.w * inv);
    // A fragment-major scatter (unchanged from round 5, verified)
    int t  = row >> 6, rf = (row >> 5) & 1, l31r = row & 31;
    int sl = l >> 2, lh2 = (l >> 1) & 1, half = l & 1;
    int lane = lh2 * 32 + l31r;
    ((uint2*)cbhf)[(((t * 16 + sl) * 2 + rf) << 7) + lane * 2 + half] = pk.u;
  } else if (bid < 5120) {
    int idx = (bid - 1024) * 256 + threadIdx.x;   // uint4 id, [0, 1048576)
    const float4* xs = (const float4*)x;
    float4 a = xs[idx * 2];
    float4 b = xs[idx * 2 + 1];
    union { _Float16 h[8]; uint4 u; } pk;
    pk.h[0] = (_Float16)a.x; pk.h[1] = (_Float16)a.y;
    pk.h[2] = (_Float16)a.z; pk.h[3] = (_Float16)a.w;
    pk.h[4] = (_Float16)b.x; pk.h[5] = (_Float16)b.y;
    pk.h[6] = (_Float16)b.z; pk.h[7] = (_Float16)b.w;
    // B fragment-major: row's 16B chunk c -> (rowgrp, sl=c>>1, lh=c&1)
    int row = idx >> 5, c = idx & 31;
    int rowgrp = row >> 5, l31r = row & 31, sl = c >> 1, lhh = c & 1;
    ((uint4*)xhf)[((size_t)rowgrp * 16 + sl) * 64 + lhh * 32 + l31r] = pk.u;
  } else {
    for (int k = threadIdx.x; k < NLAT; k += 256) hist[k] = 0;
  }
}

// MFMA GEMM (codes x batch) + per-row top-4 candidate keys.
// v6: grid 1024 (4 blocks/CU -> 4 waves/SIMD), 32 rows/wave, no LDS,
// no barriers, fragment-major A and B (all loads coalesced). acc biased
// +32 -> branchless packed-key top-3 scan: 5-op u32 sorted insert with
// the code index embedded in the low 12 bits (no tree, no branch, no
// separate index registers).
__global__ __launch_bounds__(256, 4) void vq_gemm_kernel(
    const char* __restrict__ xhf, const char* __restrict__ cbhf,
    uint* __restrict__ keys) {
  const int tid = threadIdx.x;
  const int w = tid >> 6, l = tid & 63;
  const int l31 = l & 31, lh = l >> 5;
  const int bb = blockIdx.x >> 2, q = blockIdx.x & 3;
  const int wrow0 = bb * 128 + w * 32;
  const int cbase = q * 1024;
  const uint lh4u = (uint)(lh << 2);

  // ---- x fragments (full K=256), coalesced 1KB loads, stay resident ----
  const char* xb = xhf + ((size_t)(bb * 4 + w) * 1024 + l) * 16;
  f16x8 xf[16];
  #pragma unroll
  for (int s2 = 0; s2 < 16; ++s2) xf[s2] = *(const f16x8*)(xb + s2 * 1024);

  // ---- A-stream: linear walk, 2-slot register ring (4-wave TLP hides) ----
  const char* qbase = cbhf + (size_t)q * 524288 + (size_t)l * 16;
  f16x8 ring[2][2];
  ring[0][0] = *(const f16x8*)(qbase);
  ring[0][1] = *(const f16x8*)(qbase + 1024);
  const char* pp = qbase + 2048;

  uint k1 = 0, k2 = 0, k3 = 0;   // packed top-3 (u32 order = value order)

  #pragma unroll 1
  for (int t = 0; t < 16; ++t) {
    f32x16 acc[2];
    #pragma unroll
    for (int r = 0; r < 16; ++r) { acc[0][r] = 32.0f; acc[1][r] = 32.0f; }

    #pragma unroll
    for (int sl = 0; sl < 16; ++sl) {
      // prefetch next step (tail overruns <=2KB into next quarter/cbinv:
      // valid ws memory, values never consumed)
      ring[(sl + 1) & 1][0] = *(const f16x8*)(pp);
      ring[(sl + 1) & 1][1] = *(const f16x8*)(pp + 1024);
      pp += 2048;
      acc[0] = __builtin_amdgcn_mfma_f32_32x32x16_f16(
          ring[sl & 1][0], xf[sl], acc[0], 0, 0, 0);
      acc[1] = __builtin_amdgcn_mfma_f32_32x32x16_f16(
          ring[sl & 1][1], xf[sl], acc[1], 0, 0, 0);
    }

    // branchless packed-key top-3 update (7 VALU/value, flat)
    const uint scode = (uint)(cbase + t * 64);
    #pragma unroll
    for (int rf = 0; rf < 2; ++rf) {
      #pragma unroll
      for (int r = 0; r < 16; ++r) {
        const uint cr = (uint)(rf * 32 + (r & 3) + 8 * (r >> 2));
        uint key = (__float_as_uint(acc[rf][r]) & 0xFFFFF000u)
                 | scode | cr | lh4u;
        uint m1 = max(k1, key), n1 = min(k1, key); k1 = m1;
        uint m2 = max(k2, n1),  n2 = min(k2, n1);  k2 = m2;
        k3 = max(k3, n2);
      }
    }
  }

  // ---- merge lane pair (l, l^32) -> top-4 keys, one uint4 store ----
  uint o1 = __shfl_xor(k1, 32, 64);
  uint o2 = __shfl_xor(k2, 32, 64);
  uint o3 = __shfl_xor(k3, 32, 64);
  uint k4 = 0;
  #pragma unroll
  for (int e = 0; e < 3; ++e) {
    uint o = (e == 0) ? o1 : (e == 1) ? o2 : o3;
    uint m = max(k1, o), n = min(k1, o); k1 = m;
    m = max(k2, n); n = min(k2, n); k2 = m;
    m = max(k3, n); n = min(k3, n); k3 = m;
    k4 = max(k4, n);
  }
  if (lh == 0) {
    uint4 kv; kv.x = k1; kv.y = k2; kv.z = k3; kv.w = k4;
    *(uint4*)(keys + (size_t)(wrow0 + l31) * 16 + q * 4) = kv;
  }
}

// Screened rescore: decode 16 candidate keys, exact-rescore only those
// within the rigorous error window; per-block SSE partial (no atomic).
__global__ __launch_bounds__(256) void rescore_kernel(
    const float* __restrict__ x, const float* __restrict__ cb,
    const float* __restrict__ cbinv, const uint* __restrict__ keys,
    float* __restrict__ zq, float* __restrict__ out_idx,
    int* __restrict__ hist, double* __restrict__ psse) {
  __shared__ float part[4];
  int tid = threadIdx.x, w = tid >> 6, l = tid & 63;
  int row = blockIdx.x * 4 + w;
  const float4* xr = (const float4*)(x + (size_t)row * DIM);
  float4 xv = xr[l];
  float s0 = xv.x * xv.x + xv.y * xv.y + xv.z * xv.z + xv.w * xv.w;
  #pragma unroll
  for (int m = 32; m; m >>= 1) s0 += __shfl_xor(s0, m, 64);
  float xnorm = sqrtf(s0);
  float xinv = 1.0f / fmaxf(xnorm, 1e-12f);

  uint key = keys[row * 16 + (l & 15)];
  uint kmax = key;
  #pragma unroll
  for (int m = 1; m < 16; m <<= 1) {
    uint o = __shfl_xor(kmax, m, 64);
    kmax = (o > kmax) ? o : kmax;
  }
  float dmax = kdec(kmax);   // biased by +32; compares below are relative
  float thr = dmax - 2.0f * (3e-3f * xnorm);
  bool inwin = (kdec(key) >= thr) && (l < 16);
  unsigned long long mask = __ballot(inwin);
  int besti;
  if (__popcll(mask) == 1) {
    besti = (int)(kmax & 0xFFFu);       // provably the exact argmax
  } else {
    float bestv = -3e38f; besti = 0x7fffffff;
    unsigned long long mm = mask;
    while (mm) {
      int b = __ffsll(mm) - 1; mm &= mm - 1;
      int ci = (int)(__shfl(key, b, 64) & 0xFFFu);
      float cbi = cbinv[ci];
      const float4* cr = (const float4*)(cb + (size_t)ci * DIM);
      float4 cv = cr[l];
      float d = (xv.x * xinv) * (cv.x * cbi) + (xv.y * xinv) * (cv.y * cbi)
              + (xv.z * xinv) * (cv.z * cbi) + (xv.w * xinv) * (cv.w * cbi);
      #pragma unroll
      for (int m = 32; m; m >>= 1) d += __shfl_xor(d, m, 64);
      bool better = (d > bestv) || (d == bestv && ci < besti);
      bestv = better ? d : bestv;
      besti = better ? ci : besti;
    }
  }

  float4 zv = ((const float4*)(cb + (size_t)besti * DIM))[l];
  float4 o;
  o.x = xv.x + (zv.x - xv.x); o.y = xv.y + (zv.y - xv.y);
  o.z = xv.z + (zv.z - xv.z); o.w = xv.w + (zv.w - xv.w);
  ((float4*)(zq + (size_t)row * DIM))[l] = o;
  float dx = xv.x - zv.x, dy = xv.y - zv.y, dz = xv.z - zv.z, dw = xv.w - zv.w;
  float s = dx * dx + dy * dy + dz * dz + dw * dw;
  #pragma unroll
  for (int m = 32; m; m >>= 1) s += __shfl_xor(s, m, 64);
  if (l == 0) part[w] = s;
  __syncthreads();
  if (tid == 0)
    psse[blockIdx.x] = (double)((part[0] + part[1]) + (part[2] + part[3]));
  if (l == 0) {
    atomicAdd(&hist[besti], 1);
    out_idx[row] = (float)besti;
  }
}

// Entropy from histogram + SSE partial reduction + final scalar losses.
__global__ __launch_bounds__(256) void finalize_kernel(
    const int* __restrict__ hist, const double* __restrict__ psse,
    float* __restrict__ outs) {
  int tid = threadIdx.x;
  double e = 0.0, s = 0.0;
  for (int k = tid; k < NLAT; k += 256) {
    int c = hist[k];
    if (c > 0) {
      float p = (float)c * (1.0f / 32768.0f);
      e += (double)(p * logf(p));
    }
  }
  for (int k = tid; k < BATCH / 4; k += 256) s += psse[k];
  #pragma unroll
  for (int off = 32; off; off >>= 1) {
    e += __shfl_xor(e, off, 64);
    s += __shfl_xor(s, off, 64);
  }
  __shared__ double pe[4], ps[4];
  int w = tid >> 6, l = tid & 63;
  if (l == 0) { pe[w] = e; ps[w] = s; }
  __syncthreads();
  if (tid == 0) {
    double H = -((pe[0] + pe[1]) + (pe[2] + pe[3]));
    double sse = (ps[0] + ps[1]) + (ps[2] + ps[3]);
    double qv = sse * (1.0 / ((double)BATCH * (double)DIM));
    float qf = (float)qv;
    float Hf = (float)H;
    float ent_loss = -Hf;
    float vq = qf + 0.25f * qf + 0.1f * ent_loss;
    outs[0] = vq;
    outs[1] = qf;
    outs[2] = qf;
    outs[3] = ent_loss;
    outs[4] = Hf;
  }
}

extern "C" void kernel_launch(void* const* d_in, const int* in_sizes, int n_in,
                              void* d_out, int out_size, void* d_ws, size_t ws_size,
                              hipStream_t stream) {
  const float* x  = (const float*)d_in[0];
  const float* cb = (const float*)d_in[1];

  float* out     = (float*)d_out;
  float* zq      = out;
  float* scalars = out + (size_t)BATCH * DIM;
  float* oidx    = scalars + 5;

  char* wsb = (char*)d_ws;
  ushort* cbhf  = (ushort*)(wsb + WS_CBH);
  float*  cbinv = (float*)(wsb + WS_CBINV);
  uint*   keys  = (uint*)(wsb + WS_KEYS);
  int*    hist  = (int*)(wsb + WS_HIST);
  // per-block SSE partials reuse the cbhf region (dead after vq_gemm)
  double* psse  = (double*)(wsb + WS_CBH);

  // fp16 fragment-major x scratch in the first 16 MB of the zq output
  ushort* xhf = (ushort*)d_out;

  prep_kernel<<<5121, 256, 0, stream>>>(x, cb, cbhf, cbinv, xhf, hist);
  vq_gemm_kernel<<<1024, 256, 0, stream>>>((const char*)xhf,
                                           (const char*)cbhf, keys);
  rescore_kernel<<<BATCH / 4, 256, 0, stream>>>(x, cb, cbinv, keys,
                                                zq, oidx, hist, psse);
  finalize_kernel<<<1, 256, 0, stream>>>(hist, psse, scalars);
}